// Round 15
// baseline (308.698 us; speedup 1.0000x reference)
//
#include <hip/hip_runtime.h>
#include <hip/hip_fp16.h>

#define DIM 64
#define BIN_SHIFT 7
#define BINSZ 128      // nodes per bin
#define MAXBINS 1024   // supports N up to 131072
#define PB 512         // edge-slice blocks for hist/bucket (power of 2)
#define PB_LOG 9

// ---------------- pass 1: per-block LDS histogram -> C[blk][bin] ----------------

__global__ __launch_bounds__(256) void k_hist(const int* __restrict__ dst,
                                              int* __restrict__ C, int E, int NB) {
    __shared__ int h[MAXBINS];
    for (int i = threadIdx.x; i < NB; i += 256) h[i] = 0;
    __syncthreads();
    int per = (E + PB - 1) / PB;
    int e0 = blockIdx.x * per;
    int e1 = e0 + per; if (e1 > E) e1 = E;
    for (int e = e0 + (int)threadIdx.x; e < e1; e += 256)
        atomicAdd(&h[dst[e] >> BIN_SHIFT], 1);
    __syncthreads();
    for (int i = threadIdx.x; i < NB; i += 256)
        C[blockIdx.x * NB + i] = h[i];
}

// ---------------- pass 2a: chunk-local exclusive scan of C (bin-major order) ----------------

__global__ __launch_bounds__(1024) void k_scanA(const int* __restrict__ C,
                                                int* __restrict__ S,
                                                int* __restrict__ bsums, int NB, int M) {
    __shared__ int sh[1024];
    int tid = threadIdx.x;
    int j0 = blockIdx.x * 4096 + tid * 4;
    int v[4]; int sum = 0;
#pragma unroll
    for (int t = 0; t < 4; ++t) {
        int j = j0 + t; int x = 0;
        if (j < M) { int bin = j >> PB_LOG, blk = j & (PB - 1); x = C[blk * NB + bin]; }
        v[t] = sum; sum += x;
    }
    sh[tid] = sum;
    __syncthreads();
#pragma unroll
    for (int d = 1; d < 1024; d <<= 1) {
        int t = (tid >= d) ? sh[tid - d] : 0;
        __syncthreads();
        sh[tid] += t;
        __syncthreads();
    }
    int excl = sh[tid] - sum;
#pragma unroll
    for (int t = 0; t < 4; ++t) {
        int j = j0 + t;
        if (j < M) S[j] = excl + v[t];
    }
    if (tid == 1023) bsums[blockIdx.x] = sh[1023];
}

// ---------------- pass 2b: exclusive scan of chunk sums ----------------

__global__ __launch_bounds__(1024) void k_scanB(int* __restrict__ bsums, int nb) {
    __shared__ int s[1024];
    int tid = threadIdx.x;
    int v = (tid < nb) ? bsums[tid] : 0;
    s[tid] = v;
    __syncthreads();
#pragma unroll
    for (int d = 1; d < 1024; d <<= 1) {
        int t = (tid >= d) ? s[tid - d] : 0;
        __syncthreads();
        s[tid] += t;
        __syncthreads();
    }
    if (tid < nb) bsums[tid] = s[tid] - v;
}

// ---------------- pass 3: one-pass bucket scatter, LDS cursors ----------------

__global__ __launch_bounds__(256) void k_bucket(const int* __restrict__ src,
                                                const int* __restrict__ dst,
                                                const int* __restrict__ S,
                                                const int* __restrict__ bsums,
                                                int* __restrict__ bkt, int E, int NB) {
    __shared__ int lcur[MAXBINS];
    int blk = blockIdx.x;
    for (int i = threadIdx.x; i < NB; i += 256) {
        int j = i * PB + blk;
        lcur[i] = S[j] + bsums[j >> 12];
    }
    __syncthreads();
    int per = (E + PB - 1) / PB;
    int e0 = blk * per;
    int e1 = e0 + per; if (e1 > E) e1 = E;
    for (int e = e0 + (int)threadIdx.x; e < e1; e += 256) {
        int d = dst[e];
        int pos = atomicAdd(&lcur[d >> BIN_SHIFT], 1);
        bkt[pos] = src[e] | ((d & (BINSZ - 1)) << 24);
    }
}

// ---------------- pass 4: per-bin counting sort (shfl scan) -> csr, off, dinv; + gbound ----------------

__global__ __launch_bounds__(256) void k_binsort(const int* __restrict__ bkt,
                                                 const int* __restrict__ S,
                                                 const int* __restrict__ bsums,
                                                 int* __restrict__ csr,
                                                 int* __restrict__ off,
                                                 float* __restrict__ dinv,
                                                 const int* __restrict__ batch,
                                                 int* __restrict__ goff,
                                                 int N, int G, int E, int NB) {
    __shared__ int cnt[BINSZ], bas[BINSZ], cur[BINSZ];
    __shared__ int wsum[4];
    int tid = threadIdx.x;
    int b = blockIdx.x;
    int j0 = b << PB_LOG;
    int s0 = S[j0] + bsums[j0 >> 12];
    int s1 = E;
    if (b + 1 < NB) { int j1 = (b + 1) << PB_LOG; s1 = S[j1] + bsums[j1 >> 12]; }
    if (tid < BINSZ) { cnt[tid] = 0; cur[tid] = 0; }
    __syncthreads();
    for (int i = s0 + tid; i < s1; i += 256)
        atomicAdd(&cnt[(bkt[i] >> 24) & (BINSZ - 1)], 1);
    __syncthreads();
    int my = (tid < BINSZ) ? cnt[tid] : 0;
    int lane = tid & 63, wv = tid >> 6;
    int x = my;
#pragma unroll
    for (int d = 1; d < 64; d <<= 1) {
        int t = __shfl_up(x, d);
        if (lane >= d) x += t;
    }
    if (lane == 63) wsum[wv] = x;
    __syncthreads();
    int prefix = 0;
    for (int w = 0; w < wv; ++w) prefix += wsum[w];
    int ex = x + prefix - my;               // exclusive base
    if (tid < BINSZ) {
        bas[tid] = ex;
        int v = (b << BIN_SHIFT) + tid;
        if (v < N) {
            off[v] = s0 + ex;
            dinv[v] = rsqrtf((float)(my + 1));   // +1 self-loop
            if (v == N - 1) off[N] = E;
            // fused gbound (batch sorted)
            int bb = batch[v];
            int prev = (v == 0) ? -1 : batch[v - 1];
            for (int g = prev + 1; g <= bb; ++g) goff[g] = v;
            if (v == N - 1)
                for (int g = bb + 1; g <= G; ++g) goff[g] = N;
        }
    }
    __syncthreads();
    for (int i = s0 + tid; i < s1; i += 256) {
        int p = bkt[i];
        int lo = (p >> 24) & (BINSZ - 1);
        int li = atomicAdd(&cur[lo], 1);
        csr[s0 + bas[lo] + li] = p & 0xFFFFFF;
    }
}

// ---------------- skinny GEMM (64-row blocks): hs[row] = (act(X[row]) @ W) * dinv[row] ----------------
// Xs padded to 65 floats/row (breaks the 4-way bank conflict on row-offset reads)

__global__ __launch_bounds__(256) void k_gemm(const float* __restrict__ Xf,
                                              const __half* __restrict__ Xh,
                                              const float* __restrict__ W,
                                              const float* __restrict__ dinv,
                                              __half* __restrict__ Y, int N, int relu_in) {
    __shared__ float Ws[64 * 64];
    __shared__ float Xs[64 * 65];
    int tid = threadIdx.x;
#pragma unroll
    for (int i = 0; i < 16; ++i) Ws[tid + 256 * i] = W[tid + 256 * i];

    int row0 = blockIdx.x * 64;
#pragma unroll
    for (int i = 0; i < 4; ++i) {
        int slot = tid + 256 * i;              // float4 slot 0..1023
        int r = slot >> 4, cc = (slot & 15) << 2;
        int row = row0 + r;
        float4 vv = make_float4(0.f, 0.f, 0.f, 0.f);
        if (row < N) {
            if (Xh) {
                uint2 u = *(const uint2*)(Xh + (size_t)row * DIM + cc);
                float2 f0 = __half22float2(*(__half2*)&u.x);
                float2 f1 = __half22float2(*(__half2*)&u.y);
                vv = make_float4(f0.x, f0.y, f1.x, f1.y);
            } else {
                vv = *(const float4*)(Xf + (size_t)row * DIM + cc);
            }
            if (relu_in) {
                vv.x = fmaxf(vv.x, 0.f); vv.y = fmaxf(vv.y, 0.f);
                vv.z = fmaxf(vv.z, 0.f); vv.w = fmaxf(vv.w, 0.f);
            }
        }
        *(float4*)(Xs + r * 65 + cc) = vv;
    }
    __syncthreads();

    int c4 = (tid & 15) << 2;
    int rb = (tid >> 4) << 2;                   // 0,4,...,60
    float sc0 = (row0 + rb + 0 < N) ? dinv[row0 + rb + 0] : 0.f;
    float sc1 = (row0 + rb + 1 < N) ? dinv[row0 + rb + 1] : 0.f;
    float sc2 = (row0 + rb + 2 < N) ? dinv[row0 + rb + 2] : 0.f;
    float sc3 = (row0 + rb + 3 < N) ? dinv[row0 + rb + 3] : 0.f;

    float4 a0 = make_float4(0.f, 0.f, 0.f, 0.f), a1 = a0, a2 = a0, a3 = a0;
#pragma unroll
    for (int k = 0; k < 64; ++k) {
        float4 w = *(const float4*)(Ws + k * DIM + c4);
        float x0 = Xs[(rb + 0) * 65 + k];
        float x1 = Xs[(rb + 1) * 65 + k];
        float x2 = Xs[(rb + 2) * 65 + k];
        float x3 = Xs[(rb + 3) * 65 + k];
        a0.x += x0 * w.x; a0.y += x0 * w.y; a0.z += x0 * w.z; a0.w += x0 * w.w;
        a1.x += x1 * w.x; a1.y += x1 * w.y; a1.z += x1 * w.z; a1.w += x1 * w.w;
        a2.x += x2 * w.x; a2.y += x2 * w.y; a2.z += x2 * w.z; a2.w += x2 * w.w;
        a3.x += x3 * w.x; a3.y += x3 * w.y; a3.z += x3 * w.z; a3.w += x3 * w.w;
    }

#pragma unroll
    for (int i = 0; i < 4; ++i) {
        int row = row0 + rb + i;
        float4 a = (i == 0) ? a0 : (i == 1) ? a1 : (i == 2) ? a2 : a3;
        float s = (i == 0) ? sc0 : (i == 1) ? sc1 : (i == 2) ? sc2 : sc3;
        if (row < N) {
            __half2 p0 = __floats2half2_rn(a.x * s, a.y * s);
            __half2 p1 = __floats2half2_rn(a.z * s, a.w * s);
            uint2 u;
            u.x = *(unsigned int*)&p0;
            u.y = *(unsigned int*)&p1;
            *(uint2*)(Y + (size_t)row * DIM + c4) = u;
        } else if (row == N) {
            uint2 z; z.x = 0u; z.y = 0u;
            *(uint2*)(Y + (size_t)row * DIM + c4) = z;
        }
    }
}

// ---------------- gather: agg[v] = dv*(hs[v] + sum hs[nbr]) + bias (fp16 out, pre-relu) ----------------
// one 64-lane wave per node; 16-lane quarters x uint2; 16 edges/iter, dual accumulators
// dv and bias hoisted off the post-reduce critical path

__global__ __launch_bounds__(256) void k_gather(const __half* __restrict__ hs,
                                                const int* __restrict__ csr_src,
                                                const int* __restrict__ off,
                                                const float* __restrict__ dinv,
                                                const float* __restrict__ bias,
                                                __half* __restrict__ agg, int N) {
    int v = (blockIdx.x * 256 + threadIdx.x) >> 6;
    int lane = threadIdx.x & 63;
    if (v >= N) return;
    int q = lane >> 4, c = lane & 15;
    const uint2* h2 = (const uint2*)hs;
    float dv = dinv[v];                          // hoisted (independent of edge loop)
    float4 bv = ((const float4*)bias)[c];        // hoisted

    float4 accA = make_float4(0.f, 0.f, 0.f, 0.f);
    float4 accB = make_float4(0.f, 0.f, 0.f, 0.f);
    if (q == 0) {                          // self-loop term hs[v]
        uint2 u = h2[(size_t)v * 16 + c];
        float2 f0 = __half22float2(*(__half2*)&u.x);
        float2 f1 = __half22float2(*(__half2*)&u.y);
        accA = make_float4(f0.x, f0.y, f1.x, f1.y);
    }

    int k0 = off[v], k1 = off[v + 1];
    for (int kb = k0; kb < k1; kb += 64) {
        int m = k1 - kb;
        int idx = N;                       // zero row for padding lanes
        if (lane < m) idx = csr_src[kb + lane];
        int mlim = m > 64 ? 64 : m;
        int mm = (mlim + 15) & ~15;
        for (int j = 0; j < mm; j += 16) { // 16 edges per iter: 4 8B gathers in flight
            int sA = __shfl(idx, j + q);
            int sB = __shfl(idx, j + 4 + q);
            int sC = __shfl(idx, j + 8 + q);
            int sD = __shfl(idx, j + 12 + q);
            uint2 uA = h2[(size_t)sA * 16 + c];
            uint2 uB = h2[(size_t)sB * 16 + c];
            uint2 uC = h2[(size_t)sC * 16 + c];
            uint2 uD = h2[(size_t)sD * 16 + c];
            float2 a0 = __half22float2(*(__half2*)&uA.x);
            float2 a1 = __half22float2(*(__half2*)&uA.y);
            float2 b0 = __half22float2(*(__half2*)&uB.x);
            float2 b1 = __half22float2(*(__half2*)&uB.y);
            float2 c0 = __half22float2(*(__half2*)&uC.x);
            float2 c1 = __half22float2(*(__half2*)&uC.y);
            float2 d0 = __half22float2(*(__half2*)&uD.x);
            float2 d1 = __half22float2(*(__half2*)&uD.y);
            accA.x += a0.x + b0.x; accA.y += a0.y + b0.y;
            accA.z += a1.x + b1.x; accA.w += a1.y + b1.y;
            accB.x += c0.x + d0.x; accB.y += c0.y + d0.y;
            accB.z += c1.x + d1.x; accB.w += c1.y + d1.y;
        }
    }
    float4 acc = make_float4(accA.x + accB.x, accA.y + accB.y,
                             accA.z + accB.z, accA.w + accB.w);
    // reduce quarters: lanes (c, c+16, c+32, c+48) -> lane c
    acc.x += __shfl_down(acc.x, 32); acc.y += __shfl_down(acc.y, 32);
    acc.z += __shfl_down(acc.z, 32); acc.w += __shfl_down(acc.w, 32);
    acc.x += __shfl_down(acc.x, 16); acc.y += __shfl_down(acc.y, 16);
    acc.z += __shfl_down(acc.z, 16); acc.w += __shfl_down(acc.w, 16);
    if (q == 0) {
        __half2 p0 = __floats2half2_rn(acc.x * dv + bv.x, acc.y * dv + bv.y);
        __half2 p1 = __floats2half2_rn(acc.z * dv + bv.z, acc.w * dv + bv.w);
        uint2 u;
        u.x = *(unsigned int*)&p0;
        u.y = *(unsigned int*)&p1;
        ((uint2*)(agg + (size_t)v * DIM))[c] = u;
    }
}

// ---------------- pool: out[g] = mean relu(agg2[v]) (fp16 input) ----------------

__global__ __launch_bounds__(256) void k_pool(const __half* __restrict__ agg,
                                              const int* __restrict__ goff,
                                              float* __restrict__ out, int G) {
    int g = blockIdx.x * 4 + (threadIdx.x >> 6);
    if (g >= G) return;
    int lane = threadIdx.x & 63;
    int q = lane >> 4, c = lane & 15;
    const uint2* h2 = (const uint2*)agg;
    int n0 = goff[g], n1 = goff[g + 1];
    float4 acc = make_float4(0.f, 0.f, 0.f, 0.f);
    for (int i = n0 + q; i < n1; i += 4) {
        uint2 u = h2[(size_t)i * 16 + c];
        float2 f0 = __half22float2(*(__half2*)&u.x);
        float2 f1 = __half22float2(*(__half2*)&u.y);
        acc.x += fmaxf(f0.x, 0.f); acc.y += fmaxf(f0.y, 0.f);
        acc.z += fmaxf(f1.x, 0.f); acc.w += fmaxf(f1.y, 0.f);
    }
    acc.x += __shfl_down(acc.x, 32); acc.y += __shfl_down(acc.y, 32);
    acc.z += __shfl_down(acc.z, 32); acc.w += __shfl_down(acc.w, 32);
    acc.x += __shfl_down(acc.x, 16); acc.y += __shfl_down(acc.y, 16);
    acc.z += __shfl_down(acc.z, 16); acc.w += __shfl_down(acc.w, 16);
    if (q == 0) {
        float inv = 1.0f / fmaxf((float)(n1 - n0), 1.0f);
        *(float4*)(out + ((size_t)g << 6) + (c << 2)) =
            make_float4(acc.x * inv, acc.y * inv, acc.z * inv, acc.w * inv);
    }
}

// ---------------- launch ----------------

static inline int cdiv(int a, int b) { return (a + b - 1) / b; }

extern "C" void kernel_launch(void* const* d_in, const int* in_sizes, int n_in,
                              void* d_out, int out_size, void* d_ws, size_t ws_size,
                              hipStream_t stream) {
    const float* x   = (const float*)d_in[0];
    const float* W1  = (const float*)d_in[1];
    const float* b1  = (const float*)d_in[2];
    const float* W2  = (const float*)d_in[3];
    const float* b2  = (const float*)d_in[4];
    const int*   ei  = (const int*)d_in[5];
    const int*   bat = (const int*)d_in[6];

    const int N = in_sizes[0] / DIM;
    const int E = in_sizes[5] / 2;
    const int G = out_size / DIM;
    const int NB = cdiv(N, BINSZ);           // <= MAXBINS
    const int M  = NB * PB;                  // scan length
    const int* src = ei;
    const int* dst = ei + E;
    float* out = (float*)d_out;

    // workspace: hs1 | hs2 | agg1 | dinv | off | goff | C | S | bsums | csr
    // bkt aliases hs1 (dead before gemm1); agg2 aliases hs1 (dead after gather1).
    __half* hs1    = (__half*)d_ws;                         // (N+1)*64 h
    __half* hs2    = hs1 + (size_t)(N + 1) * DIM;           // (N+1)*64 h
    __half* agg1   = hs2 + (size_t)(N + 1) * DIM;           // N*64 h
    float*  dinv   = (float*)(agg1 + (size_t)N * DIM);      // N f
    int*    off    = (int*)(dinv + N);                      // N+1 i
    int*    goff   = off + (N + 1);                         // G+1 i
    int*    C      = goff + (G + 1);                        // PB*NB i
    int*    S      = C + (size_t)PB * NB;                   // PB*NB i
    int*    bsums  = S + (size_t)PB * NB;                   // up to 1024 i
    int*    csr    = bsums + 1024;                          // E i
    int*    bkt    = (int*)hs1;                             // E i (aliased)
    __half* agg2   = hs1;                                   // N*64 h (aliased)

    k_hist<<<PB, 256, 0, stream>>>(dst, C, E, NB);
    int nb2 = cdiv(M, 4096);
    k_scanA<<<nb2, 1024, 0, stream>>>(C, S, bsums, NB, M);
    k_scanB<<<1, 1024, 0, stream>>>(bsums, nb2);
    k_bucket<<<PB, 256, 0, stream>>>(src, dst, S, bsums, bkt, E, NB);
    k_binsort<<<NB, 256, 0, stream>>>(bkt, S, bsums, csr, off, dinv, bat, goff, N, G, E, NB);

    // layer 1: hs1 = (x @ W1) * dinv ; agg1 = gather(hs1) + b1 (fp16, pre-relu)
    k_gemm<<<cdiv(N + 1, 64), 256, 0, stream>>>(x, nullptr, W1, dinv, hs1, N, 0);
    k_gather<<<cdiv(N, 4), 256, 0, stream>>>(hs1, csr, off, dinv, b1, agg1, N);

    // layer 2: hs2 = (relu(agg1) @ W2) * dinv ; agg2 = gather(hs2) + b2 (fp16, pre-relu)
    k_gemm<<<cdiv(N + 1, 64), 256, 0, stream>>>(nullptr, agg1, W2, dinv, hs2, N, 1);
    k_gather<<<cdiv(N, 4), 256, 0, stream>>>(hs2, csr, off, dinv, b2, agg2, N);

    k_pool<<<cdiv(G, 4), 256, 0, stream>>>(agg2, goff, out, G);
}

// Round 16
// 263.124 us; speedup vs baseline: 1.1732x; 1.1732x over previous
//
#include <hip/hip_runtime.h>
#include <hip/hip_fp16.h>

#define DIM 64
#define BIN_SHIFT 7
#define BINSZ 128      // nodes per bin
#define MAXBINS 1024   // supports N up to 131072
#define PB 512         // edge-slice blocks for hist/bucket (power of 2)
#define PB_LOG 9

// ---------------- pass 1: per-block LDS histogram -> C[blk][bin] ----------------

__global__ __launch_bounds__(256) void k_hist(const int* __restrict__ dst,
                                              int* __restrict__ C, int E, int NB) {
    __shared__ int h[MAXBINS];
    for (int i = threadIdx.x; i < NB; i += 256) h[i] = 0;
    __syncthreads();
    int per = (E + PB - 1) / PB;
    int e0 = blockIdx.x * per;
    int e1 = e0 + per; if (e1 > E) e1 = E;
    for (int e = e0 + (int)threadIdx.x; e < e1; e += 256)
        atomicAdd(&h[dst[e] >> BIN_SHIFT], 1);
    __syncthreads();
    for (int i = threadIdx.x; i < NB; i += 256)
        C[blockIdx.x * NB + i] = h[i];
}

// ---------------- pass 2a: chunk-local exclusive scan of C (bin-major order) ----------------

__global__ __launch_bounds__(1024) void k_scanA(const int* __restrict__ C,
                                                int* __restrict__ S,
                                                int* __restrict__ bsums, int NB, int M) {
    __shared__ int sh[1024];
    int tid = threadIdx.x;
    int j0 = blockIdx.x * 4096 + tid * 4;
    int v[4]; int sum = 0;
#pragma unroll
    for (int t = 0; t < 4; ++t) {
        int j = j0 + t; int x = 0;
        if (j < M) { int bin = j >> PB_LOG, blk = j & (PB - 1); x = C[blk * NB + bin]; }
        v[t] = sum; sum += x;
    }
    sh[tid] = sum;
    __syncthreads();
#pragma unroll
    for (int d = 1; d < 1024; d <<= 1) {
        int t = (tid >= d) ? sh[tid - d] : 0;
        __syncthreads();
        sh[tid] += t;
        __syncthreads();
    }
    int excl = sh[tid] - sum;
#pragma unroll
    for (int t = 0; t < 4; ++t) {
        int j = j0 + t;
        if (j < M) S[j] = excl + v[t];
    }
    if (tid == 1023) bsums[blockIdx.x] = sh[1023];
}

// ---------------- pass 2b: exclusive scan of chunk sums ----------------

__global__ __launch_bounds__(1024) void k_scanB(int* __restrict__ bsums, int nb) {
    __shared__ int s[1024];
    int tid = threadIdx.x;
    int v = (tid < nb) ? bsums[tid] : 0;
    s[tid] = v;
    __syncthreads();
#pragma unroll
    for (int d = 1; d < 1024; d <<= 1) {
        int t = (tid >= d) ? s[tid - d] : 0;
        __syncthreads();
        s[tid] += t;
        __syncthreads();
    }
    if (tid < nb) bsums[tid] = s[tid] - v;
}

// ---------------- pass 3: one-pass bucket scatter, LDS cursors ----------------

__global__ __launch_bounds__(256) void k_bucket(const int* __restrict__ src,
                                                const int* __restrict__ dst,
                                                const int* __restrict__ S,
                                                const int* __restrict__ bsums,
                                                int* __restrict__ bkt, int E, int NB) {
    __shared__ int lcur[MAXBINS];
    int blk = blockIdx.x;
    for (int i = threadIdx.x; i < NB; i += 256) {
        int j = i * PB + blk;
        lcur[i] = S[j] + bsums[j >> 12];
    }
    __syncthreads();
    int per = (E + PB - 1) / PB;
    int e0 = blk * per;
    int e1 = e0 + per; if (e1 > E) e1 = E;
    for (int e = e0 + (int)threadIdx.x; e < e1; e += 256) {
        int d = dst[e];
        int pos = atomicAdd(&lcur[d >> BIN_SHIFT], 1);
        bkt[pos] = src[e] | ((d & (BINSZ - 1)) << 24);
    }
}

// ---------------- pass 4: per-bin counting sort (shfl scan) -> csr, off, dinv; + gbound ----------------

__global__ __launch_bounds__(256) void k_binsort(const int* __restrict__ bkt,
                                                 const int* __restrict__ S,
                                                 const int* __restrict__ bsums,
                                                 int* __restrict__ csr,
                                                 int* __restrict__ off,
                                                 float* __restrict__ dinv,
                                                 const int* __restrict__ batch,
                                                 int* __restrict__ goff,
                                                 int N, int G, int E, int NB) {
    __shared__ int cnt[BINSZ], bas[BINSZ], cur[BINSZ];
    __shared__ int wsum[4];
    int tid = threadIdx.x;
    int b = blockIdx.x;
    int j0 = b << PB_LOG;
    int s0 = S[j0] + bsums[j0 >> 12];
    int s1 = E;
    if (b + 1 < NB) { int j1 = (b + 1) << PB_LOG; s1 = S[j1] + bsums[j1 >> 12]; }
    if (tid < BINSZ) { cnt[tid] = 0; cur[tid] = 0; }
    __syncthreads();
    for (int i = s0 + tid; i < s1; i += 256)
        atomicAdd(&cnt[(bkt[i] >> 24) & (BINSZ - 1)], 1);
    __syncthreads();
    int my = (tid < BINSZ) ? cnt[tid] : 0;
    int lane = tid & 63, wv = tid >> 6;
    int x = my;
#pragma unroll
    for (int d = 1; d < 64; d <<= 1) {
        int t = __shfl_up(x, d);
        if (lane >= d) x += t;
    }
    if (lane == 63) wsum[wv] = x;
    __syncthreads();
    int prefix = 0;
    for (int w = 0; w < wv; ++w) prefix += wsum[w];
    int ex = x + prefix - my;               // exclusive base
    if (tid < BINSZ) {
        bas[tid] = ex;
        int v = (b << BIN_SHIFT) + tid;
        if (v < N) {
            off[v] = s0 + ex;
            dinv[v] = rsqrtf((float)(my + 1));   // +1 self-loop
            if (v == N - 1) off[N] = E;
            // fused gbound (batch sorted)
            int bb = batch[v];
            int prev = (v == 0) ? -1 : batch[v - 1];
            for (int g = prev + 1; g <= bb; ++g) goff[g] = v;
            if (v == N - 1)
                for (int g = bb + 1; g <= G; ++g) goff[g] = N;
        }
    }
    __syncthreads();
    for (int i = s0 + tid; i < s1; i += 256) {
        int p = bkt[i];
        int lo = (p >> 24) & (BINSZ - 1);
        int li = atomicAdd(&cur[lo], 1);
        csr[s0 + bas[lo] + li] = p & 0xFFFFFF;
    }
}

// ---------------- skinny GEMM (16-row blocks, R14-proven): hs[row] = (act(X[row]) @ W) * dinv[row] ----------------

__global__ __launch_bounds__(256) void k_gemm(const float* __restrict__ Xf,
                                              const __half* __restrict__ Xh,
                                              const float* __restrict__ W,
                                              const float* __restrict__ dinv,
                                              __half* __restrict__ Y, int N, int relu_in) {
    __shared__ float Ws[64 * 64];
    __shared__ float Xs[16 * 64];
    int tid = threadIdx.x;
#pragma unroll
    for (int i = 0; i < 16; ++i) Ws[tid + 256 * i] = W[tid + 256 * i];

    int row0 = blockIdx.x * 16;
    int r = tid >> 4, c4 = (tid & 15) << 2;
    int row = row0 + r;
    {
        float4 v = make_float4(0.f, 0.f, 0.f, 0.f);
        if (row < N) {
            if (Xh) {
                uint2 u = *(const uint2*)(Xh + (size_t)row * DIM + c4);
                float2 f0 = __half22float2(*(__half2*)&u.x);
                float2 f1 = __half22float2(*(__half2*)&u.y);
                v = make_float4(f0.x, f0.y, f1.x, f1.y);
            } else {
                v = *(const float4*)(Xf + (size_t)row * DIM + c4);
            }
            if (relu_in) {
                v.x = fmaxf(v.x, 0.f); v.y = fmaxf(v.y, 0.f);
                v.z = fmaxf(v.z, 0.f); v.w = fmaxf(v.w, 0.f);
            }
        }
        *(float4*)(Xs + r * DIM + c4) = v;
    }
    __syncthreads();

    float4 acc = make_float4(0.f, 0.f, 0.f, 0.f);
#pragma unroll
    for (int k = 0; k < 64; ++k) {
        float xk = Xs[r * DIM + k];
        float4 w = *(const float4*)(Ws + k * DIM + c4);
        acc.x += xk * w.x; acc.y += xk * w.y;
        acc.z += xk * w.z; acc.w += xk * w.w;
    }
    if (row < N) {
        float s = dinv[row];
        __half2 p0 = __floats2half2_rn(acc.x * s, acc.y * s);
        __half2 p1 = __floats2half2_rn(acc.z * s, acc.w * s);
        uint2 u;
        u.x = *(unsigned int*)&p0;
        u.y = *(unsigned int*)&p1;
        *(uint2*)(Y + (size_t)row * DIM + c4) = u;
    } else if (row == N) {
        uint2 z; z.x = 0u; z.y = 0u;
        *(uint2*)(Y + (size_t)row * DIM + c4) = z;
    }
}

// ---------------- gather: agg[v] = dv*(hs[v] + sum hs[nbr]) + bias (fp16 out, pre-relu) ----------------
// one 64-lane wave per node; 16-lane quarters x uint2; 16 edges/iter, dual accumulators
// dv and bias hoisted off the post-reduce critical path

__global__ __launch_bounds__(256) void k_gather(const __half* __restrict__ hs,
                                                const int* __restrict__ csr_src,
                                                const int* __restrict__ off,
                                                const float* __restrict__ dinv,
                                                const float* __restrict__ bias,
                                                __half* __restrict__ agg, int N) {
    int v = (blockIdx.x * 256 + threadIdx.x) >> 6;
    int lane = threadIdx.x & 63;
    if (v >= N) return;
    int q = lane >> 4, c = lane & 15;
    const uint2* h2 = (const uint2*)hs;
    float dv = dinv[v];                          // hoisted
    float4 bv = ((const float4*)bias)[c];        // hoisted

    float4 accA = make_float4(0.f, 0.f, 0.f, 0.f);
    float4 accB = make_float4(0.f, 0.f, 0.f, 0.f);
    if (q == 0) {                          // self-loop term hs[v]
        uint2 u = h2[(size_t)v * 16 + c];
        float2 f0 = __half22float2(*(__half2*)&u.x);
        float2 f1 = __half22float2(*(__half2*)&u.y);
        accA = make_float4(f0.x, f0.y, f1.x, f1.y);
    }

    int k0 = off[v], k1 = off[v + 1];
    for (int kb = k0; kb < k1; kb += 64) {
        int m = k1 - kb;
        int idx = N;                       // zero row for padding lanes
        if (lane < m) idx = csr_src[kb + lane];
        int mlim = m > 64 ? 64 : m;
        int mm = (mlim + 15) & ~15;
        for (int j = 0; j < mm; j += 16) { // 16 edges per iter: 4 8B gathers in flight
            int sA = __shfl(idx, j + q);
            int sB = __shfl(idx, j + 4 + q);
            int sC = __shfl(idx, j + 8 + q);
            int sD = __shfl(idx, j + 12 + q);
            uint2 uA = h2[(size_t)sA * 16 + c];
            uint2 uB = h2[(size_t)sB * 16 + c];
            uint2 uC = h2[(size_t)sC * 16 + c];
            uint2 uD = h2[(size_t)sD * 16 + c];
            float2 a0 = __half22float2(*(__half2*)&uA.x);
            float2 a1 = __half22float2(*(__half2*)&uA.y);
            float2 b0 = __half22float2(*(__half2*)&uB.x);
            float2 b1 = __half22float2(*(__half2*)&uB.y);
            float2 c0 = __half22float2(*(__half2*)&uC.x);
            float2 c1 = __half22float2(*(__half2*)&uC.y);
            float2 d0 = __half22float2(*(__half2*)&uD.x);
            float2 d1 = __half22float2(*(__half2*)&uD.y);
            accA.x += a0.x + b0.x; accA.y += a0.y + b0.y;
            accA.z += a1.x + b1.x; accA.w += a1.y + b1.y;
            accB.x += c0.x + d0.x; accB.y += c0.y + d0.y;
            accB.z += c1.x + d1.x; accB.w += c1.y + d1.y;
        }
    }
    float4 acc = make_float4(accA.x + accB.x, accA.y + accB.y,
                             accA.z + accB.z, accA.w + accB.w);
    // reduce quarters: lanes (c, c+16, c+32, c+48) -> lane c
    acc.x += __shfl_down(acc.x, 32); acc.y += __shfl_down(acc.y, 32);
    acc.z += __shfl_down(acc.z, 32); acc.w += __shfl_down(acc.w, 32);
    acc.x += __shfl_down(acc.x, 16); acc.y += __shfl_down(acc.y, 16);
    acc.z += __shfl_down(acc.z, 16); acc.w += __shfl_down(acc.w, 16);
    if (q == 0) {
        __half2 p0 = __floats2half2_rn(acc.x * dv + bv.x, acc.y * dv + bv.y);
        __half2 p1 = __floats2half2_rn(acc.z * dv + bv.z, acc.w * dv + bv.w);
        uint2 u;
        u.x = *(unsigned int*)&p0;
        u.y = *(unsigned int*)&p1;
        ((uint2*)(agg + (size_t)v * DIM))[c] = u;
    }
}

// ---------------- pool: out[g] = mean relu(agg2[v]) (fp16 input) ----------------

__global__ __launch_bounds__(256) void k_pool(const __half* __restrict__ agg,
                                              const int* __restrict__ goff,
                                              float* __restrict__ out, int G) {
    int g = blockIdx.x * 4 + (threadIdx.x >> 6);
    if (g >= G) return;
    int lane = threadIdx.x & 63;
    int q = lane >> 4, c = lane & 15;
    const uint2* h2 = (const uint2*)agg;
    int n0 = goff[g], n1 = goff[g + 1];
    float4 acc = make_float4(0.f, 0.f, 0.f, 0.f);
    for (int i = n0 + q; i < n1; i += 4) {
        uint2 u = h2[(size_t)i * 16 + c];
        float2 f0 = __half22float2(*(__half2*)&u.x);
        float2 f1 = __half22float2(*(__half2*)&u.y);
        acc.x += fmaxf(f0.x, 0.f); acc.y += fmaxf(f0.y, 0.f);
        acc.z += fmaxf(f1.x, 0.f); acc.w += fmaxf(f1.y, 0.f);
    }
    acc.x += __shfl_down(acc.x, 32); acc.y += __shfl_down(acc.y, 32);
    acc.z += __shfl_down(acc.z, 32); acc.w += __shfl_down(acc.w, 32);
    acc.x += __shfl_down(acc.x, 16); acc.y += __shfl_down(acc.y, 16);
    acc.z += __shfl_down(acc.z, 16); acc.w += __shfl_down(acc.w, 16);
    if (q == 0) {
        float inv = 1.0f / fmaxf((float)(n1 - n0), 1.0f);
        *(float4*)(out + ((size_t)g << 6) + (c << 2)) =
            make_float4(acc.x * inv, acc.y * inv, acc.z * inv, acc.w * inv);
    }
}

// ---------------- launch ----------------

static inline int cdiv(int a, int b) { return (a + b - 1) / b; }

extern "C" void kernel_launch(void* const* d_in, const int* in_sizes, int n_in,
                              void* d_out, int out_size, void* d_ws, size_t ws_size,
                              hipStream_t stream) {
    const float* x   = (const float*)d_in[0];
    const float* W1  = (const float*)d_in[1];
    const float* b1  = (const float*)d_in[2];
    const float* W2  = (const float*)d_in[3];
    const float* b2  = (const float*)d_in[4];
    const int*   ei  = (const int*)d_in[5];
    const int*   bat = (const int*)d_in[6];

    const int N = in_sizes[0] / DIM;
    const int E = in_sizes[5] / 2;
    const int G = out_size / DIM;
    const int NB = cdiv(N, BINSZ);           // <= MAXBINS
    const int M  = NB * PB;                  // scan length
    const int* src = ei;
    const int* dst = ei + E;
    float* out = (float*)d_out;

    // workspace: hs1 | hs2 | agg1 | dinv | off | goff | C | S | bsums | csr
    // bkt aliases hs1 (dead before gemm1); agg2 aliases hs1 (dead after gather1).
    __half* hs1    = (__half*)d_ws;                         // (N+1)*64 h
    __half* hs2    = hs1 + (size_t)(N + 1) * DIM;           // (N+1)*64 h
    __half* agg1   = hs2 + (size_t)(N + 1) * DIM;           // N*64 h
    float*  dinv   = (float*)(agg1 + (size_t)N * DIM);      // N f
    int*    off    = (int*)(dinv + N);                      // N+1 i
    int*    goff   = off + (N + 1);                         // G+1 i
    int*    C      = goff + (G + 1);                        // PB*NB i
    int*    S      = C + (size_t)PB * NB;                   // PB*NB i
    int*    bsums  = S + (size_t)PB * NB;                   // up to 1024 i
    int*    csr    = bsums + 1024;                          // E i
    int*    bkt    = (int*)hs1;                             // E i (aliased)
    __half* agg2   = hs1;                                   // N*64 h (aliased)

    k_hist<<<PB, 256, 0, stream>>>(dst, C, E, NB);
    int nb2 = cdiv(M, 4096);
    k_scanA<<<nb2, 1024, 0, stream>>>(C, S, bsums, NB, M);
    k_scanB<<<1, 1024, 0, stream>>>(bsums, nb2);
    k_bucket<<<PB, 256, 0, stream>>>(src, dst, S, bsums, bkt, E, NB);
    k_binsort<<<NB, 256, 0, stream>>>(bkt, S, bsums, csr, off, dinv, bat, goff, N, G, E, NB);

    // layer 1: hs1 = (x @ W1) * dinv ; agg1 = gather(hs1) + b1 (fp16, pre-relu)
    k_gemm<<<cdiv(N + 1, 16), 256, 0, stream>>>(x, nullptr, W1, dinv, hs1, N, 0);
    k_gather<<<cdiv(N, 4), 256, 0, stream>>>(hs1, csr, off, dinv, b1, agg1, N);

    // layer 2: hs2 = (relu(agg1) @ W2) * dinv ; agg2 = gather(hs2) + b2 (fp16, pre-relu)
    k_gemm<<<cdiv(N + 1, 16), 256, 0, stream>>>(nullptr, agg1, W2, dinv, hs2, N, 1);
    k_gather<<<cdiv(N, 4), 256, 0, stream>>>(hs2, csr, off, dinv, b2, agg2, N);

    k_pool<<<cdiv(G, 4), 256, 0, stream>>>(agg2, goff, out, G);
}

// Round 17
// 259.227 us; speedup vs baseline: 1.1908x; 1.0150x over previous
//
#include <hip/hip_runtime.h>
#include <hip/hip_fp16.h>

#define DIM 64
#define BIN_SHIFT 7
#define BINSZ 128      // nodes per bin
#define MAXBINS 1024   // supports N up to 131072
#define PB 512         // edge-slice blocks for hist/bucket (power of 2)
#define PB_LOG 9

typedef __attribute__((ext_vector_type(2))) float floatx2;

// ---------------- pass 1: per-block LDS histogram -> C[blk][bin] ----------------

__global__ __launch_bounds__(256) void k_hist(const int* __restrict__ dst,
                                              int* __restrict__ C, int E, int NB) {
    __shared__ int h[MAXBINS];
    for (int i = threadIdx.x; i < NB; i += 256) h[i] = 0;
    __syncthreads();
    int per = (E + PB - 1) / PB;
    int e0 = blockIdx.x * per;
    int e1 = e0 + per; if (e1 > E) e1 = E;
    for (int e = e0 + (int)threadIdx.x; e < e1; e += 256)
        atomicAdd(&h[dst[e] >> BIN_SHIFT], 1);
    __syncthreads();
    for (int i = threadIdx.x; i < NB; i += 256)
        C[blockIdx.x * NB + i] = h[i];
}

// ---------------- pass 2a: chunk-local exclusive scan of C (bin-major order) ----------------

__global__ __launch_bounds__(1024) void k_scanA(const int* __restrict__ C,
                                                int* __restrict__ S,
                                                int* __restrict__ bsums, int NB, int M) {
    __shared__ int sh[1024];
    int tid = threadIdx.x;
    int j0 = blockIdx.x * 4096 + tid * 4;
    int v[4]; int sum = 0;
#pragma unroll
    for (int t = 0; t < 4; ++t) {
        int j = j0 + t; int x = 0;
        if (j < M) { int bin = j >> PB_LOG, blk = j & (PB - 1); x = C[blk * NB + bin]; }
        v[t] = sum; sum += x;
    }
    sh[tid] = sum;
    __syncthreads();
#pragma unroll
    for (int d = 1; d < 1024; d <<= 1) {
        int t = (tid >= d) ? sh[tid - d] : 0;
        __syncthreads();
        sh[tid] += t;
        __syncthreads();
    }
    int excl = sh[tid] - sum;
#pragma unroll
    for (int t = 0; t < 4; ++t) {
        int j = j0 + t;
        if (j < M) S[j] = excl + v[t];
    }
    if (tid == 1023) bsums[blockIdx.x] = sh[1023];
}

// ---------------- pass 2b: exclusive scan of chunk sums ----------------

__global__ __launch_bounds__(1024) void k_scanB(int* __restrict__ bsums, int nb) {
    __shared__ int s[1024];
    int tid = threadIdx.x;
    int v = (tid < nb) ? bsums[tid] : 0;
    s[tid] = v;
    __syncthreads();
#pragma unroll
    for (int d = 1; d < 1024; d <<= 1) {
        int t = (tid >= d) ? s[tid - d] : 0;
        __syncthreads();
        s[tid] += t;
        __syncthreads();
    }
    if (tid < nb) bsums[tid] = s[tid] - v;
}

// ---------------- pass 3: one-pass bucket scatter, LDS cursors ----------------

__global__ __launch_bounds__(256) void k_bucket(const int* __restrict__ src,
                                                const int* __restrict__ dst,
                                                const int* __restrict__ S,
                                                const int* __restrict__ bsums,
                                                int* __restrict__ bkt, int E, int NB) {
    __shared__ int lcur[MAXBINS];
    int blk = blockIdx.x;
    for (int i = threadIdx.x; i < NB; i += 256) {
        int j = i * PB + blk;
        lcur[i] = S[j] + bsums[j >> 12];
    }
    __syncthreads();
    int per = (E + PB - 1) / PB;
    int e0 = blk * per;
    int e1 = e0 + per; if (e1 > E) e1 = E;
    for (int e = e0 + (int)threadIdx.x; e < e1; e += 256) {
        int d = dst[e];
        int pos = atomicAdd(&lcur[d >> BIN_SHIFT], 1);
        bkt[pos] = src[e] | ((d & (BINSZ - 1)) << 24);
    }
}

// ---------------- pass 4: per-bin counting sort (shfl scan) -> csr, off, dinv; + gbound ----------------

__global__ __launch_bounds__(256) void k_binsort(const int* __restrict__ bkt,
                                                 const int* __restrict__ S,
                                                 const int* __restrict__ bsums,
                                                 int* __restrict__ csr,
                                                 int* __restrict__ off,
                                                 float* __restrict__ dinv,
                                                 const int* __restrict__ batch,
                                                 int* __restrict__ goff,
                                                 int N, int G, int E, int NB) {
    __shared__ int cnt[BINSZ], bas[BINSZ], cur[BINSZ];
    __shared__ int wsum[4];
    int tid = threadIdx.x;
    int b = blockIdx.x;
    int j0 = b << PB_LOG;
    int s0 = S[j0] + bsums[j0 >> 12];
    int s1 = E;
    if (b + 1 < NB) { int j1 = (b + 1) << PB_LOG; s1 = S[j1] + bsums[j1 >> 12]; }
    if (tid < BINSZ) { cnt[tid] = 0; cur[tid] = 0; }
    __syncthreads();
    for (int i = s0 + tid; i < s1; i += 256)
        atomicAdd(&cnt[(bkt[i] >> 24) & (BINSZ - 1)], 1);
    __syncthreads();
    int my = (tid < BINSZ) ? cnt[tid] : 0;
    int lane = tid & 63, wv = tid >> 6;
    int x = my;
#pragma unroll
    for (int d = 1; d < 64; d <<= 1) {
        int t = __shfl_up(x, d);
        if (lane >= d) x += t;
    }
    if (lane == 63) wsum[wv] = x;
    __syncthreads();
    int prefix = 0;
    for (int w = 0; w < wv; ++w) prefix += wsum[w];
    int ex = x + prefix - my;               // exclusive base
    if (tid < BINSZ) {
        bas[tid] = ex;
        int v = (b << BIN_SHIFT) + tid;
        if (v < N) {
            off[v] = s0 + ex;
            dinv[v] = rsqrtf((float)(my + 1));   // +1 self-loop
            if (v == N - 1) off[N] = E;
            // fused gbound (batch sorted)
            int bb = batch[v];
            int prev = (v == 0) ? -1 : batch[v - 1];
            for (int g = prev + 1; g <= bb; ++g) goff[g] = v;
            if (v == N - 1)
                for (int g = bb + 1; g <= G; ++g) goff[g] = N;
        }
    }
    __syncthreads();
    for (int i = s0 + tid; i < s1; i += 256) {
        int p = bkt[i];
        int lo = (p >> 24) & (BINSZ - 1);
        int li = atomicAdd(&cur[lo], 1);
        csr[s0 + bas[lo] + li] = p & 0xFFFFFF;
    }
}

// ---------------- skinny GEMM (16-row blocks): hs[row] = (act(X[row]) @ W) * dinv[row] ----------------
// fp8out=0: fp16 output (uint2/row-chunk). fp8out=1: fp8 e4m3 output (uint/row-chunk).

__global__ __launch_bounds__(256) void k_gemm(const float* __restrict__ Xf,
                                              const __half* __restrict__ Xh,
                                              const float* __restrict__ W,
                                              const float* __restrict__ dinv,
                                              __half* __restrict__ Y, int N,
                                              int relu_in, int fp8out) {
    __shared__ float Ws[64 * 64];
    __shared__ float Xs[16 * 64];
    int tid = threadIdx.x;
#pragma unroll
    for (int i = 0; i < 16; ++i) Ws[tid + 256 * i] = W[tid + 256 * i];

    int row0 = blockIdx.x * 16;
    int r = tid >> 4, c4 = (tid & 15) << 2;
    int row = row0 + r;
    {
        float4 v = make_float4(0.f, 0.f, 0.f, 0.f);
        if (row < N) {
            if (Xh) {
                uint2 u = *(const uint2*)(Xh + (size_t)row * DIM + c4);
                float2 f0 = __half22float2(*(__half2*)&u.x);
                float2 f1 = __half22float2(*(__half2*)&u.y);
                v = make_float4(f0.x, f0.y, f1.x, f1.y);
            } else {
                v = *(const float4*)(Xf + (size_t)row * DIM + c4);
            }
            if (relu_in) {
                v.x = fmaxf(v.x, 0.f); v.y = fmaxf(v.y, 0.f);
                v.z = fmaxf(v.z, 0.f); v.w = fmaxf(v.w, 0.f);
            }
        }
        *(float4*)(Xs + r * DIM + c4) = v;
    }
    __syncthreads();

    float4 acc = make_float4(0.f, 0.f, 0.f, 0.f);
#pragma unroll
    for (int k = 0; k < 64; ++k) {
        float xk = Xs[r * DIM + k];
        float4 w = *(const float4*)(Ws + k * DIM + c4);
        acc.x += xk * w.x; acc.y += xk * w.y;
        acc.z += xk * w.z; acc.w += xk * w.w;
    }
    if (fp8out) {
        unsigned int* Y8 = (unsigned int*)Y;     // 16 uints per row
        if (row < N) {
            float s = dinv[row];
            int p = 0;
            p = __builtin_amdgcn_cvt_pk_fp8_f32(acc.x * s, acc.y * s, p, false);
            p = __builtin_amdgcn_cvt_pk_fp8_f32(acc.z * s, acc.w * s, p, true);
            Y8[(size_t)row * 16 + (c4 >> 2)] = (unsigned int)p;
        } else if (row == N) {
            Y8[(size_t)row * 16 + (c4 >> 2)] = 0u;   // +0 in e4m3
        }
    } else {
        if (row < N) {
            float s = dinv[row];
            __half2 p0 = __floats2half2_rn(acc.x * s, acc.y * s);
            __half2 p1 = __floats2half2_rn(acc.z * s, acc.w * s);
            uint2 u;
            u.x = *(unsigned int*)&p0;
            u.y = *(unsigned int*)&p1;
            *(uint2*)(Y + (size_t)row * DIM + c4) = u;
        } else if (row == N) {
            uint2 z; z.x = 0u; z.y = 0u;
            *(uint2*)(Y + (size_t)row * DIM + c4) = z;
        }
    }
}

// ---------------- gather (fp16 rows): agg[v] = dv*(hs[v] + sum hs[nbr]) + bias ----------------
// one 64-lane wave per node; 16-lane quarters x uint2; 16 edges/iter, dual accumulators

__global__ __launch_bounds__(256) void k_gather(const __half* __restrict__ hs,
                                                const int* __restrict__ csr_src,
                                                const int* __restrict__ off,
                                                const float* __restrict__ dinv,
                                                const float* __restrict__ bias,
                                                __half* __restrict__ agg, int N) {
    int v = (blockIdx.x * 256 + threadIdx.x) >> 6;
    int lane = threadIdx.x & 63;
    if (v >= N) return;
    int q = lane >> 4, c = lane & 15;
    const uint2* h2 = (const uint2*)hs;
    float dv = dinv[v];                          // hoisted
    float4 bv = ((const float4*)bias)[c];        // hoisted

    float4 accA = make_float4(0.f, 0.f, 0.f, 0.f);
    float4 accB = make_float4(0.f, 0.f, 0.f, 0.f);
    if (q == 0) {                          // self-loop term hs[v]
        uint2 u = h2[(size_t)v * 16 + c];
        float2 f0 = __half22float2(*(__half2*)&u.x);
        float2 f1 = __half22float2(*(__half2*)&u.y);
        accA = make_float4(f0.x, f0.y, f1.x, f1.y);
    }

    int k0 = off[v], k1 = off[v + 1];
    for (int kb = k0; kb < k1; kb += 64) {
        int m = k1 - kb;
        int idx = N;                       // zero row for padding lanes
        if (lane < m) idx = csr_src[kb + lane];
        int mlim = m > 64 ? 64 : m;
        int mm = (mlim + 15) & ~15;
        for (int j = 0; j < mm; j += 16) { // 16 edges per iter: 4 8B gathers in flight
            int sA = __shfl(idx, j + q);
            int sB = __shfl(idx, j + 4 + q);
            int sC = __shfl(idx, j + 8 + q);
            int sD = __shfl(idx, j + 12 + q);
            uint2 uA = h2[(size_t)sA * 16 + c];
            uint2 uB = h2[(size_t)sB * 16 + c];
            uint2 uC = h2[(size_t)sC * 16 + c];
            uint2 uD = h2[(size_t)sD * 16 + c];
            float2 a0 = __half22float2(*(__half2*)&uA.x);
            float2 a1 = __half22float2(*(__half2*)&uA.y);
            float2 b0 = __half22float2(*(__half2*)&uB.x);
            float2 b1 = __half22float2(*(__half2*)&uB.y);
            float2 c0 = __half22float2(*(__half2*)&uC.x);
            float2 c1 = __half22float2(*(__half2*)&uC.y);
            float2 d0 = __half22float2(*(__half2*)&uD.x);
            float2 d1 = __half22float2(*(__half2*)&uD.y);
            accA.x += a0.x + b0.x; accA.y += a0.y + b0.y;
            accA.z += a1.x + b1.x; accA.w += a1.y + b1.y;
            accB.x += c0.x + d0.x; accB.y += c0.y + d0.y;
            accB.z += c1.x + d1.x; accB.w += c1.y + d1.y;
        }
    }
    float4 acc = make_float4(accA.x + accB.x, accA.y + accB.y,
                             accA.z + accB.z, accA.w + accB.w);
    acc.x += __shfl_down(acc.x, 32); acc.y += __shfl_down(acc.y, 32);
    acc.z += __shfl_down(acc.z, 32); acc.w += __shfl_down(acc.w, 32);
    acc.x += __shfl_down(acc.x, 16); acc.y += __shfl_down(acc.y, 16);
    acc.z += __shfl_down(acc.z, 16); acc.w += __shfl_down(acc.w, 16);
    if (q == 0) {
        __half2 p0 = __floats2half2_rn(acc.x * dv + bv.x, acc.y * dv + bv.y);
        __half2 p1 = __floats2half2_rn(acc.z * dv + bv.z, acc.w * dv + bv.w);
        uint2 u;
        u.x = *(unsigned int*)&p0;
        u.y = *(unsigned int*)&p1;
        ((uint2*)(agg + (size_t)v * DIM))[c] = u;
    }
}

// ---------------- gather8 (fp8 e4m3 rows, 64B/row): halves compulsory L2-miss traffic ----------------

__global__ __launch_bounds__(256) void k_gather8(const unsigned int* __restrict__ hs8,
                                                 const int* __restrict__ csr_src,
                                                 const int* __restrict__ off,
                                                 const float* __restrict__ dinv,
                                                 const float* __restrict__ bias,
                                                 __half* __restrict__ agg, int N) {
    int v = (blockIdx.x * 256 + threadIdx.x) >> 6;
    int lane = threadIdx.x & 63;
    if (v >= N) return;
    int q = lane >> 4, c = lane & 15;            // lane c owns cols 4c..4c+3 (one uint)
    float dv = dinv[v];                          // hoisted
    float4 bv = ((const float4*)bias)[c];        // hoisted

    float4 accA = make_float4(0.f, 0.f, 0.f, 0.f);
    float4 accB = make_float4(0.f, 0.f, 0.f, 0.f);
    if (q == 0) {                          // self-loop term
        unsigned int u = hs8[(size_t)v * 16 + c];
        floatx2 f0 = __builtin_amdgcn_cvt_pk_f32_fp8((int)u, false);
        floatx2 f1 = __builtin_amdgcn_cvt_pk_f32_fp8((int)u, true);
        accA = make_float4(f0.x, f0.y, f1.x, f1.y);
    }

    int k0 = off[v], k1 = off[v + 1];
    for (int kb = k0; kb < k1; kb += 64) {
        int m = k1 - kb;
        int idx = N;                       // zero row for padding lanes
        if (lane < m) idx = csr_src[kb + lane];
        int mlim = m > 64 ? 64 : m;
        int mm = (mlim + 15) & ~15;
        for (int j = 0; j < mm; j += 16) { // 16 edges per iter: 4 4B gathers in flight
            int sA = __shfl(idx, j + q);
            int sB = __shfl(idx, j + 4 + q);
            int sC = __shfl(idx, j + 8 + q);
            int sD = __shfl(idx, j + 12 + q);
            unsigned int uA = hs8[(size_t)sA * 16 + c];
            unsigned int uB = hs8[(size_t)sB * 16 + c];
            unsigned int uC = hs8[(size_t)sC * 16 + c];
            unsigned int uD = hs8[(size_t)sD * 16 + c];
            floatx2 a0 = __builtin_amdgcn_cvt_pk_f32_fp8((int)uA, false);
            floatx2 a1 = __builtin_amdgcn_cvt_pk_f32_fp8((int)uA, true);
            floatx2 b0 = __builtin_amdgcn_cvt_pk_f32_fp8((int)uB, false);
            floatx2 b1 = __builtin_amdgcn_cvt_pk_f32_fp8((int)uB, true);
            floatx2 c0 = __builtin_amdgcn_cvt_pk_f32_fp8((int)uC, false);
            floatx2 c1 = __builtin_amdgcn_cvt_pk_f32_fp8((int)uC, true);
            floatx2 d0 = __builtin_amdgcn_cvt_pk_f32_fp8((int)uD, false);
            floatx2 d1 = __builtin_amdgcn_cvt_pk_f32_fp8((int)uD, true);
            accA.x += a0.x + b0.x; accA.y += a0.y + b0.y;
            accA.z += a1.x + b1.x; accA.w += a1.y + b1.y;
            accB.x += c0.x + d0.x; accB.y += c0.y + d0.y;
            accB.z += c1.x + d1.x; accB.w += c1.y + d1.y;
        }
    }
    float4 acc = make_float4(accA.x + accB.x, accA.y + accB.y,
                             accA.z + accB.z, accA.w + accB.w);
    acc.x += __shfl_down(acc.x, 32); acc.y += __shfl_down(acc.y, 32);
    acc.z += __shfl_down(acc.z, 32); acc.w += __shfl_down(acc.w, 32);
    acc.x += __shfl_down(acc.x, 16); acc.y += __shfl_down(acc.y, 16);
    acc.z += __shfl_down(acc.z, 16); acc.w += __shfl_down(acc.w, 16);
    if (q == 0) {
        __half2 p0 = __floats2half2_rn(acc.x * dv + bv.x, acc.y * dv + bv.y);
        __half2 p1 = __floats2half2_rn(acc.z * dv + bv.z, acc.w * dv + bv.w);
        uint2 u;
        u.x = *(unsigned int*)&p0;
        u.y = *(unsigned int*)&p1;
        ((uint2*)(agg + (size_t)v * DIM))[c] = u;
    }
}

// ---------------- pool: out[g] = mean relu(agg2[v]) (fp16 input) ----------------

__global__ __launch_bounds__(256) void k_pool(const __half* __restrict__ agg,
                                              const int* __restrict__ goff,
                                              float* __restrict__ out, int G) {
    int g = blockIdx.x * 4 + (threadIdx.x >> 6);
    if (g >= G) return;
    int lane = threadIdx.x & 63;
    int q = lane >> 4, c = lane & 15;
    const uint2* h2 = (const uint2*)agg;
    int n0 = goff[g], n1 = goff[g + 1];
    float4 acc = make_float4(0.f, 0.f, 0.f, 0.f);
    for (int i = n0 + q; i < n1; i += 4) {
        uint2 u = h2[(size_t)i * 16 + c];
        float2 f0 = __half22float2(*(__half2*)&u.x);
        float2 f1 = __half22float2(*(__half2*)&u.y);
        acc.x += fmaxf(f0.x, 0.f); acc.y += fmaxf(f0.y, 0.f);
        acc.z += fmaxf(f1.x, 0.f); acc.w += fmaxf(f1.y, 0.f);
    }
    acc.x += __shfl_down(acc.x, 32); acc.y += __shfl_down(acc.y, 32);
    acc.z += __shfl_down(acc.z, 32); acc.w += __shfl_down(acc.w, 32);
    acc.x += __shfl_down(acc.x, 16); acc.y += __shfl_down(acc.y, 16);
    acc.z += __shfl_down(acc.z, 16); acc.w += __shfl_down(acc.w, 16);
    if (q == 0) {
        float inv = 1.0f / fmaxf((float)(n1 - n0), 1.0f);
        *(float4*)(out + ((size_t)g << 6) + (c << 2)) =
            make_float4(acc.x * inv, acc.y * inv, acc.z * inv, acc.w * inv);
    }
}

// ---------------- launch ----------------

static inline int cdiv(int a, int b) { return (a + b - 1) / b; }

extern "C" void kernel_launch(void* const* d_in, const int* in_sizes, int n_in,
                              void* d_out, int out_size, void* d_ws, size_t ws_size,
                              hipStream_t stream) {
    const float* x   = (const float*)d_in[0];
    const float* W1  = (const float*)d_in[1];
    const float* b1  = (const float*)d_in[2];
    const float* W2  = (const float*)d_in[3];
    const float* b2  = (const float*)d_in[4];
    const int*   ei  = (const int*)d_in[5];
    const int*   bat = (const int*)d_in[6];

    const int N = in_sizes[0] / DIM;
    const int E = in_sizes[5] / 2;
    const int G = out_size / DIM;
    const int NB = cdiv(N, BINSZ);           // <= MAXBINS
    const int M  = NB * PB;                  // scan length
    const int* src = ei;
    const int* dst = ei + E;
    float* out = (float*)d_out;

    // workspace: hs1 | hs2 | agg1 | dinv | off | goff | C | S | bsums | csr
    // bkt aliases hs1 (dead before gemm1); agg2 aliases hs1 (dead after gather1).
    // hs2 region sized for fp16 but used as fp8 (64B/row) — only shrinks.
    __half* hs1    = (__half*)d_ws;                         // (N+1)*64 h
    __half* hs2    = hs1 + (size_t)(N + 1) * DIM;           // (N+1)*64 h (fp8 uses half)
    __half* agg1   = hs2 + (size_t)(N + 1) * DIM;           // N*64 h
    float*  dinv   = (float*)(agg1 + (size_t)N * DIM);      // N f
    int*    off    = (int*)(dinv + N);                      // N+1 i
    int*    goff   = off + (N + 1);                         // G+1 i
    int*    C      = goff + (G + 1);                        // PB*NB i
    int*    S      = C + (size_t)PB * NB;                   // PB*NB i
    int*    bsums  = S + (size_t)PB * NB;                   // up to 1024 i
    int*    csr    = bsums + 1024;                          // E i
    int*    bkt    = (int*)hs1;                             // E i (aliased)
    __half* agg2   = hs1;                                   // N*64 h (aliased)

    k_hist<<<PB, 256, 0, stream>>>(dst, C, E, NB);
    int nb2 = cdiv(M, 4096);
    k_scanA<<<nb2, 1024, 0, stream>>>(C, S, bsums, NB, M);
    k_scanB<<<1, 1024, 0, stream>>>(bsums, nb2);
    k_bucket<<<PB, 256, 0, stream>>>(src, dst, S, bsums, bkt, E, NB);
    k_binsort<<<NB, 256, 0, stream>>>(bkt, S, bsums, csr, off, dinv, bat, goff, N, G, E, NB);

    // layer 1: hs1 = (x @ W1) * dinv (fp16) ; agg1 = gather(hs1) + b1 (fp16, pre-relu)
    k_gemm<<<cdiv(N + 1, 16), 256, 0, stream>>>(x, nullptr, W1, dinv, hs1, N, 0, 0);
    k_gather<<<cdiv(N, 4), 256, 0, stream>>>(hs1, csr, off, dinv, b1, agg1, N);

    // layer 2: hs2 = (relu(agg1) @ W2) * dinv (fp8 e4m3) ; agg2 = gather8(hs2) + b2 (fp16)
    k_gemm<<<cdiv(N + 1, 16), 256, 0, stream>>>(nullptr, agg1, W2, dinv, hs2, N, 1, 1);
    k_gather8<<<cdiv(N, 4), 256, 0, stream>>>((const unsigned int*)hs2, csr, off, dinv, b2, agg2, N);

    k_pool<<<cdiv(G, 4), 256, 0, stream>>>(agg2, goff, out, G);
}

// Round 18
// 254.996 us; speedup vs baseline: 1.2106x; 1.0166x over previous
//
#include <hip/hip_runtime.h>
#include <hip/hip_fp16.h>

#define DIM 64
#define BIN_SHIFT 7
#define BINSZ 128      // nodes per bin
#define MAXBINS 1024   // supports N up to 131072
#define PB 512         // edge-slice blocks for hist/bucket (power of 2)
#define PB_LOG 9

typedef __attribute__((ext_vector_type(2))) float floatx2;

// ---------------- pass 1: per-block LDS histogram -> C[blk][bin] ----------------

__global__ __launch_bounds__(256) void k_hist(const int* __restrict__ dst,
                                              int* __restrict__ C, int E, int NB) {
    __shared__ int h[MAXBINS];
    for (int i = threadIdx.x; i < NB; i += 256) h[i] = 0;
    __syncthreads();
    int per = (E + PB - 1) / PB;
    int e0 = blockIdx.x * per;
    int e1 = e0 + per; if (e1 > E) e1 = E;
    for (int e = e0 + (int)threadIdx.x; e < e1; e += 256)
        atomicAdd(&h[dst[e] >> BIN_SHIFT], 1);
    __syncthreads();
    for (int i = threadIdx.x; i < NB; i += 256)
        C[blockIdx.x * NB + i] = h[i];
}

// ---------------- pass 2a: chunk-local exclusive scan of C (bin-major order) ----------------

__global__ __launch_bounds__(1024) void k_scanA(const int* __restrict__ C,
                                                int* __restrict__ S,
                                                int* __restrict__ bsums, int NB, int M) {
    __shared__ int sh[1024];
    int tid = threadIdx.x;
    int j0 = blockIdx.x * 4096 + tid * 4;
    int v[4]; int sum = 0;
#pragma unroll
    for (int t = 0; t < 4; ++t) {
        int j = j0 + t; int x = 0;
        if (j < M) { int bin = j >> PB_LOG, blk = j & (PB - 1); x = C[blk * NB + bin]; }
        v[t] = sum; sum += x;
    }
    sh[tid] = sum;
    __syncthreads();
#pragma unroll
    for (int d = 1; d < 1024; d <<= 1) {
        int t = (tid >= d) ? sh[tid - d] : 0;
        __syncthreads();
        sh[tid] += t;
        __syncthreads();
    }
    int excl = sh[tid] - sum;
#pragma unroll
    for (int t = 0; t < 4; ++t) {
        int j = j0 + t;
        if (j < M) S[j] = excl + v[t];
    }
    if (tid == 1023) bsums[blockIdx.x] = sh[1023];
}

// ---------------- pass 2b: exclusive scan of chunk sums ----------------

__global__ __launch_bounds__(1024) void k_scanB(int* __restrict__ bsums, int nb) {
    __shared__ int s[1024];
    int tid = threadIdx.x;
    int v = (tid < nb) ? bsums[tid] : 0;
    s[tid] = v;
    __syncthreads();
#pragma unroll
    for (int d = 1; d < 1024; d <<= 1) {
        int t = (tid >= d) ? s[tid - d] : 0;
        __syncthreads();
        s[tid] += t;
        __syncthreads();
    }
    if (tid < nb) bsums[tid] = s[tid] - v;
}

// ---------------- pass 3: one-pass bucket scatter, LDS cursors ----------------

__global__ __launch_bounds__(256) void k_bucket(const int* __restrict__ src,
                                                const int* __restrict__ dst,
                                                const int* __restrict__ S,
                                                const int* __restrict__ bsums,
                                                int* __restrict__ bkt, int E, int NB) {
    __shared__ int lcur[MAXBINS];
    int blk = blockIdx.x;
    for (int i = threadIdx.x; i < NB; i += 256) {
        int j = i * PB + blk;
        lcur[i] = S[j] + bsums[j >> 12];
    }
    __syncthreads();
    int per = (E + PB - 1) / PB;
    int e0 = blk * per;
    int e1 = e0 + per; if (e1 > E) e1 = E;
    for (int e = e0 + (int)threadIdx.x; e < e1; e += 256) {
        int d = dst[e];
        int pos = atomicAdd(&lcur[d >> BIN_SHIFT], 1);
        bkt[pos] = src[e] | ((d & (BINSZ - 1)) << 24);
    }
}

// ---------------- pass 4: per-bin counting sort (shfl scan) -> csr, off, dinv; + gbound ----------------

__global__ __launch_bounds__(256) void k_binsort(const int* __restrict__ bkt,
                                                 const int* __restrict__ S,
                                                 const int* __restrict__ bsums,
                                                 int* __restrict__ csr,
                                                 int* __restrict__ off,
                                                 float* __restrict__ dinv,
                                                 const int* __restrict__ batch,
                                                 int* __restrict__ goff,
                                                 int N, int G, int E, int NB) {
    __shared__ int cnt[BINSZ], bas[BINSZ], cur[BINSZ];
    __shared__ int wsum[4];
    int tid = threadIdx.x;
    int b = blockIdx.x;
    int j0 = b << PB_LOG;
    int s0 = S[j0] + bsums[j0 >> 12];
    int s1 = E;
    if (b + 1 < NB) { int j1 = (b + 1) << PB_LOG; s1 = S[j1] + bsums[j1 >> 12]; }
    if (tid < BINSZ) { cnt[tid] = 0; cur[tid] = 0; }
    __syncthreads();
    for (int i = s0 + tid; i < s1; i += 256)
        atomicAdd(&cnt[(bkt[i] >> 24) & (BINSZ - 1)], 1);
    __syncthreads();
    int my = (tid < BINSZ) ? cnt[tid] : 0;
    int lane = tid & 63, wv = tid >> 6;
    int x = my;
#pragma unroll
    for (int d = 1; d < 64; d <<= 1) {
        int t = __shfl_up(x, d);
        if (lane >= d) x += t;
    }
    if (lane == 63) wsum[wv] = x;
    __syncthreads();
    int prefix = 0;
    for (int w = 0; w < wv; ++w) prefix += wsum[w];
    int ex = x + prefix - my;               // exclusive base
    if (tid < BINSZ) {
        bas[tid] = ex;
        int v = (b << BIN_SHIFT) + tid;
        if (v < N) {
            off[v] = s0 + ex;
            dinv[v] = rsqrtf((float)(my + 1));   // +1 self-loop
            if (v == N - 1) off[N] = E;
            // fused gbound (batch sorted)
            int bb = batch[v];
            int prev = (v == 0) ? -1 : batch[v - 1];
            for (int g = prev + 1; g <= bb; ++g) goff[g] = v;
            if (v == N - 1)
                for (int g = bb + 1; g <= G; ++g) goff[g] = N;
        }
    }
    __syncthreads();
    for (int i = s0 + tid; i < s1; i += 256) {
        int p = bkt[i];
        int lo = (p >> 24) & (BINSZ - 1);
        int li = atomicAdd(&cur[lo], 1);
        csr[s0 + bas[lo] + li] = p & 0xFFFFFF;
    }
}

// ---------------- skinny GEMM (16-row blocks): hs[row] = (act(X[row]) @ W) * dinv[row] ----------------
// fp8out=1: fp8 e4m3 output (one uint per 4 cols). Row N = zeros (gather padding).

__global__ __launch_bounds__(256) void k_gemm(const float* __restrict__ Xf,
                                              const __half* __restrict__ Xh,
                                              const float* __restrict__ W,
                                              const float* __restrict__ dinv,
                                              __half* __restrict__ Y, int N,
                                              int relu_in, int fp8out) {
    __shared__ float Ws[64 * 64];
    __shared__ float Xs[16 * 64];
    int tid = threadIdx.x;
#pragma unroll
    for (int i = 0; i < 16; ++i) Ws[tid + 256 * i] = W[tid + 256 * i];

    int row0 = blockIdx.x * 16;
    int r = tid >> 4, c4 = (tid & 15) << 2;
    int row = row0 + r;
    {
        float4 v = make_float4(0.f, 0.f, 0.f, 0.f);
        if (row < N) {
            if (Xh) {
                uint2 u = *(const uint2*)(Xh + (size_t)row * DIM + c4);
                float2 f0 = __half22float2(*(__half2*)&u.x);
                float2 f1 = __half22float2(*(__half2*)&u.y);
                v = make_float4(f0.x, f0.y, f1.x, f1.y);
            } else {
                v = *(const float4*)(Xf + (size_t)row * DIM + c4);
            }
            if (relu_in) {
                v.x = fmaxf(v.x, 0.f); v.y = fmaxf(v.y, 0.f);
                v.z = fmaxf(v.z, 0.f); v.w = fmaxf(v.w, 0.f);
            }
        }
        *(float4*)(Xs + r * DIM + c4) = v;
    }
    __syncthreads();

    float4 acc = make_float4(0.f, 0.f, 0.f, 0.f);
#pragma unroll
    for (int k = 0; k < 64; ++k) {
        float xk = Xs[r * DIM + k];
        float4 w = *(const float4*)(Ws + k * DIM + c4);
        acc.x += xk * w.x; acc.y += xk * w.y;
        acc.z += xk * w.z; acc.w += xk * w.w;
    }
    if (fp8out) {
        unsigned int* Y8 = (unsigned int*)Y;     // 16 uints per row
        if (row < N) {
            float s = dinv[row];
            int p = 0;
            p = __builtin_amdgcn_cvt_pk_fp8_f32(acc.x * s, acc.y * s, p, false);
            p = __builtin_amdgcn_cvt_pk_fp8_f32(acc.z * s, acc.w * s, p, true);
            Y8[(size_t)row * 16 + (c4 >> 2)] = (unsigned int)p;
        } else if (row == N) {
            Y8[(size_t)row * 16 + (c4 >> 2)] = 0u;   // +0 in e4m3
        }
    } else {
        if (row < N) {
            float s = dinv[row];
            __half2 p0 = __floats2half2_rn(acc.x * s, acc.y * s);
            __half2 p1 = __floats2half2_rn(acc.z * s, acc.w * s);
            uint2 u;
            u.x = *(unsigned int*)&p0;
            u.y = *(unsigned int*)&p1;
            *(uint2*)(Y + (size_t)row * DIM + c4) = u;
        } else if (row == N) {
            uint2 z; z.x = 0u; z.y = 0u;
            *(uint2*)(Y + (size_t)row * DIM + c4) = z;
        }
    }
}

// ---------------- gather8 (fp8 e4m3 rows, 64B/row): halves compulsory-miss traffic ----------------
// one 64-lane wave per node; 16-lane quarters x uint; 16 edges/iter, dual accumulators

__global__ __launch_bounds__(256) void k_gather8(const unsigned int* __restrict__ hs8,
                                                 const int* __restrict__ csr_src,
                                                 const int* __restrict__ off,
                                                 const float* __restrict__ dinv,
                                                 const float* __restrict__ bias,
                                                 __half* __restrict__ agg, int N) {
    int v = (blockIdx.x * 256 + threadIdx.x) >> 6;
    int lane = threadIdx.x & 63;
    if (v >= N) return;
    int q = lane >> 4, c = lane & 15;            // lane c owns cols 4c..4c+3 (one uint)
    float dv = dinv[v];                          // hoisted
    float4 bv = ((const float4*)bias)[c];        // hoisted

    float4 accA = make_float4(0.f, 0.f, 0.f, 0.f);
    float4 accB = make_float4(0.f, 0.f, 0.f, 0.f);
    if (q == 0) {                          // self-loop term
        unsigned int u = hs8[(size_t)v * 16 + c];
        floatx2 f0 = __builtin_amdgcn_cvt_pk_f32_fp8((int)u, false);
        floatx2 f1 = __builtin_amdgcn_cvt_pk_f32_fp8((int)u, true);
        accA = make_float4(f0.x, f0.y, f1.x, f1.y);
    }

    int k0 = off[v], k1 = off[v + 1];
    for (int kb = k0; kb < k1; kb += 64) {
        int m = k1 - kb;
        int idx = N;                       // zero row for padding lanes
        if (lane < m) idx = csr_src[kb + lane];
        int mlim = m > 64 ? 64 : m;
        int mm = (mlim + 15) & ~15;
        for (int j = 0; j < mm; j += 16) { // 16 edges per iter: 4 4B gathers in flight
            int sA = __shfl(idx, j + q);
            int sB = __shfl(idx, j + 4 + q);
            int sC = __shfl(idx, j + 8 + q);
            int sD = __shfl(idx, j + 12 + q);
            unsigned int uA = hs8[(size_t)sA * 16 + c];
            unsigned int uB = hs8[(size_t)sB * 16 + c];
            unsigned int uC = hs8[(size_t)sC * 16 + c];
            unsigned int uD = hs8[(size_t)sD * 16 + c];
            floatx2 a0 = __builtin_amdgcn_cvt_pk_f32_fp8((int)uA, false);
            floatx2 a1 = __builtin_amdgcn_cvt_pk_f32_fp8((int)uA, true);
            floatx2 b0 = __builtin_amdgcn_cvt_pk_f32_fp8((int)uB, false);
            floatx2 b1 = __builtin_amdgcn_cvt_pk_f32_fp8((int)uB, true);
            floatx2 c0 = __builtin_amdgcn_cvt_pk_f32_fp8((int)uC, false);
            floatx2 c1 = __builtin_amdgcn_cvt_pk_f32_fp8((int)uC, true);
            floatx2 d0 = __builtin_amdgcn_cvt_pk_f32_fp8((int)uD, false);
            floatx2 d1 = __builtin_amdgcn_cvt_pk_f32_fp8((int)uD, true);
            accA.x += a0.x + b0.x; accA.y += a0.y + b0.y;
            accA.z += a1.x + b1.x; accA.w += a1.y + b1.y;
            accB.x += c0.x + d0.x; accB.y += c0.y + d0.y;
            accB.z += c1.x + d1.x; accB.w += c1.y + d1.y;
        }
    }
    float4 acc = make_float4(accA.x + accB.x, accA.y + accB.y,
                             accA.z + accB.z, accA.w + accB.w);
    acc.x += __shfl_down(acc.x, 32); acc.y += __shfl_down(acc.y, 32);
    acc.z += __shfl_down(acc.z, 32); acc.w += __shfl_down(acc.w, 32);
    acc.x += __shfl_down(acc.x, 16); acc.y += __shfl_down(acc.y, 16);
    acc.z += __shfl_down(acc.z, 16); acc.w += __shfl_down(acc.w, 16);
    if (q == 0) {
        __half2 p0 = __floats2half2_rn(acc.x * dv + bv.x, acc.y * dv + bv.y);
        __half2 p1 = __floats2half2_rn(acc.z * dv + bv.z, acc.w * dv + bv.w);
        uint2 u;
        u.x = *(unsigned int*)&p0;
        u.y = *(unsigned int*)&p1;
        ((uint2*)(agg + (size_t)v * DIM))[c] = u;
    }
}

// ---------------- pool: out[g] = mean relu(agg2[v]) (fp16 input) ----------------

__global__ __launch_bounds__(256) void k_pool(const __half* __restrict__ agg,
                                              const int* __restrict__ goff,
                                              float* __restrict__ out, int G) {
    int g = blockIdx.x * 4 + (threadIdx.x >> 6);
    if (g >= G) return;
    int lane = threadIdx.x & 63;
    int q = lane >> 4, c = lane & 15;
    const uint2* h2 = (const uint2*)agg;
    int n0 = goff[g], n1 = goff[g + 1];
    float4 acc = make_float4(0.f, 0.f, 0.f, 0.f);
    for (int i = n0 + q; i < n1; i += 4) {
        uint2 u = h2[(size_t)i * 16 + c];
        float2 f0 = __half22float2(*(__half2*)&u.x);
        float2 f1 = __half22float2(*(__half2*)&u.y);
        acc.x += fmaxf(f0.x, 0.f); acc.y += fmaxf(f0.y, 0.f);
        acc.z += fmaxf(f1.x, 0.f); acc.w += fmaxf(f1.y, 0.f);
    }
    acc.x += __shfl_down(acc.x, 32); acc.y += __shfl_down(acc.y, 32);
    acc.z += __shfl_down(acc.z, 32); acc.w += __shfl_down(acc.w, 32);
    acc.x += __shfl_down(acc.x, 16); acc.y += __shfl_down(acc.y, 16);
    acc.z += __shfl_down(acc.z, 16); acc.w += __shfl_down(acc.w, 16);
    if (q == 0) {
        float inv = 1.0f / fmaxf((float)(n1 - n0), 1.0f);
        *(float4*)(out + ((size_t)g << 6) + (c << 2)) =
            make_float4(acc.x * inv, acc.y * inv, acc.z * inv, acc.w * inv);
    }
}

// ---------------- launch ----------------

static inline int cdiv(int a, int b) { return (a + b - 1) / b; }

extern "C" void kernel_launch(void* const* d_in, const int* in_sizes, int n_in,
                              void* d_out, int out_size, void* d_ws, size_t ws_size,
                              hipStream_t stream) {
    const float* x   = (const float*)d_in[0];
    const float* W1  = (const float*)d_in[1];
    const float* b1  = (const float*)d_in[2];
    const float* W2  = (const float*)d_in[3];
    const float* b2  = (const float*)d_in[4];
    const int*   ei  = (const int*)d_in[5];
    const int*   bat = (const int*)d_in[6];

    const int N = in_sizes[0] / DIM;
    const int E = in_sizes[5] / 2;
    const int G = out_size / DIM;
    const int NB = cdiv(N, BINSZ);           // <= MAXBINS
    const int M  = NB * PB;                  // scan length
    const int* src = ei;
    const int* dst = ei + E;
    float* out = (float*)d_out;

    // workspace: hs1 | hs2 | agg1 | dinv | off | goff | C | S | bsums | csr
    // bkt aliases hs1 (dead before gemm1); agg2 aliases hs1 region (dead after gather1).
    // hs1/hs2 regions sized for fp16 rows; fp8 uses half of each (only shrinks).
    __half* hs1    = (__half*)d_ws;                         // (N+1)*64 h region
    __half* hs2    = hs1 + (size_t)(N + 1) * DIM;           // (N+1)*64 h region
    __half* agg1   = hs2 + (size_t)(N + 1) * DIM;           // N*64 h
    float*  dinv   = (float*)(agg1 + (size_t)N * DIM);      // N f
    int*    off    = (int*)(dinv + N);                      // N+1 i
    int*    goff   = off + (N + 1);                         // G+1 i
    int*    C      = goff + (G + 1);                        // PB*NB i
    int*    S      = C + (size_t)PB * NB;                   // PB*NB i
    int*    bsums  = S + (size_t)PB * NB;                   // up to 1024 i
    int*    csr    = bsums + 1024;                          // E i
    int*    bkt    = (int*)hs1;                             // E i (aliased)
    __half* agg2   = hs1;                                   // N*64 h (aliased)

    k_hist<<<PB, 256, 0, stream>>>(dst, C, E, NB);
    int nb2 = cdiv(M, 4096);
    k_scanA<<<nb2, 1024, 0, stream>>>(C, S, bsums, NB, M);
    k_scanB<<<1, 1024, 0, stream>>>(bsums, nb2);
    k_bucket<<<PB, 256, 0, stream>>>(src, dst, S, bsums, bkt, E, NB);
    k_binsort<<<NB, 256, 0, stream>>>(bkt, S, bsums, csr, off, dinv, bat, goff, N, G, E, NB);

    // layer 1: hs1 = (x @ W1) * dinv (fp8 e4m3) ; agg1 = gather8(hs1) + b1 (fp16, pre-relu)
    k_gemm<<<cdiv(N + 1, 16), 256, 0, stream>>>(x, nullptr, W1, dinv, hs1, N, 0, 1);
    k_gather8<<<cdiv(N, 4), 256, 0, stream>>>((const unsigned int*)hs1, csr, off, dinv, b1, agg1, N);

    // layer 2: hs2 = (relu(agg1) @ W2) * dinv (fp8 e4m3) ; agg2 = gather8(hs2) + b2 (fp16)
    k_gemm<<<cdiv(N + 1, 16), 256, 0, stream>>>(nullptr, agg1, W2, dinv, hs2, N, 1, 1);
    k_gather8<<<cdiv(N, 4), 256, 0, stream>>>((const unsigned int*)hs2, csr, off, dinv, b2, agg2, N);

    k_pool<<<cdiv(G, 4), 256, 0, stream>>>(agg2, goff, out, G);
}